// Round 5
// baseline (227.656 us; speedup 1.0000x reference)
//
#include <hip/hip_runtime.h>
#include <hip/hip_bf16.h>
#include <stdint.h>

#define HIDDEN 128

typedef __attribute__((ext_vector_type(8))) short short8;
typedef __attribute__((ext_vector_type(4))) unsigned uint4v;
typedef __attribute__((ext_vector_type(4))) float float4v;
typedef __attribute__((ext_vector_type(2))) float float2v;
typedef __attribute__((ext_vector_type(2))) unsigned uint2v;

static __device__ __forceinline__ unsigned short f2bf(float f) {
    union { float f; unsigned u; } v; v.f = f;
    unsigned r = (v.u + 0x7FFFu + ((v.u >> 16) & 1u)) >> 16;
    return (unsigned short)r;
}

// Fast pack: round-half-up (+0x8000) then byte-perm. Error bound identical to RNE
// (±0.5 ULP); only tie-breaking differs. 3 VALU per 2 floats.
static __device__ __forceinline__ unsigned pack2bf(float f0, float f1) {
    unsigned u0 = __float_as_uint(f0) + 0x8000u;
    unsigned u1 = __float_as_uint(f1) + 0x8000u;
    // result bytes [u0.b2, u0.b3, u1.b2, u1.b3]
    return __builtin_amdgcn_perm(u1, u0, 0x07060302u);
}

static __device__ __forceinline__ short8 pack8(float4v lo, float4v hi) {
    uint4v u;
    u[0] = pack2bf(lo[0], lo[1]);
    u[1] = pack2bf(lo[2], lo[3]);
    u[2] = pack2bf(hi[0], hi[1]);
    u[3] = pack2bf(hi[2], hi[3]);
    return *(short8*)&u;
}

// Kernel 1: build Wt (logical col-major combined weight, bf16, RNE) + permuted b1/W2.
// Combined W[k][j]: j<128 -> W1[k*128+j]; j>=128 -> W1[(128+k)*128+(j-128)]
// Wt[j*128+k] = W[k][j]. Permutation within each half: physical pp=m*8+tt <-> logical jj=tt*16+m.
__global__ void prep_wt(const float* __restrict__ W1, const float* __restrict__ b1,
                        const float* __restrict__ W2,
                        unsigned short* __restrict__ Wt,
                        float* __restrict__ b1p, float* __restrict__ W2p) {
    int idx = blockIdx.x * blockDim.x + threadIdx.x;   // 0 .. 32767
    if (idx < 256 * 128) {
        int j = idx >> 7, k = idx & 127;
        float v = (j < 128) ? W1[k * 128 + j] : W1[(128 + k) * 128 + (j - 128)];
        Wt[idx] = f2bf(v);
    }
    if (idx < 128) {
        int m = idx >> 3, tt = idx & 7;
        int jj = tt * 16 + m;
        b1p[idx] = b1[jj];
        W2p[idx] = W2[jj];
    }
}

// Kernel 2: Q[node][0:256] = z[node] @ W (+ b1 folded into first half), bf16, permuted layout.
// ONE 16-node m-tile per block; 4 waves cover the 256 cols (wave w -> cols w*64..w*64+63,
// B-slice register-resident). 6250 blocks = 25K waves for full latency hiding.
__global__ __launch_bounds__(256) void node_gemm(
        const float* __restrict__ z, const unsigned short* __restrict__ Wt,
        const float* __restrict__ b1p,
        unsigned short* __restrict__ Q, int n_nodes) {
    int lane = threadIdx.x & 63;
    int wave = threadIdx.x >> 6;
    int m = lane & 15;
    int quad = lane >> 4;
    int nodebase = blockIdx.x * 16;
    int row = nodebase + m;

    // B fragments (one-time, 64 VGPRs): cols wave*64 + t*16 + m
    short8 b[4][4];
    #pragma unroll
    for (int t = 0; t < 4; ++t) {
        const unsigned short* wp = Wt + (size_t)(wave * 64 + t * 16 + m) * HIDDEN;
        #pragma unroll
        for (int s = 0; s < 4; ++s)
            b[t][s] = *(const short8*)(wp + s * 32 + quad * 8);
    }

    int h   = wave >> 1;                      // 0: P1 half (bias folded), 1: P2 half
    int pp0 = m * 8 + (wave & 1) * 4;
    float4v b1v = (float4v)(0.0f);
    if (h == 0) b1v = *(const float4v*)(b1p + pp0);

    // A: lane holds A[m][k = quad*8 + j] per 32-wide k-step s
    short8 a[4];
    {
        bool ok = row < n_nodes;
        const float* zp = z + (size_t)row * HIDDEN + quad * 8;
        #pragma unroll
        for (int s = 0; s < 4; ++s) {
            float4v z0 = ok ? *(const float4v*)(zp + s * 32)     : (float4v)(0.0f);
            float4v z1 = ok ? *(const float4v*)(zp + s * 32 + 4) : (float4v)(0.0f);
            a[s] = pack8(z0, z1);
        }
    }

    float4v acc[4];
    #pragma unroll
    for (int t = 0; t < 4; ++t) acc[t] = (float4v)(0.0f);
    #pragma unroll
    for (int t = 0; t < 4; ++t)
        #pragma unroll
        for (int s = 0; s < 4; ++s)
            acc[t] = __builtin_amdgcn_mfma_f32_16x16x32_bf16(a[s], b[t][s], acc[t], 0, 0, 0);

    // C/D: node-row = quad*4 + r; lane's 4 col-tiles contiguous at physical pp0.
    #pragma unroll
    for (int r = 0; r < 4; ++r) {
        int node = nodebase + quad * 4 + r;
        if (node < n_nodes) {
            float v0 = acc[0][r] + b1v[0];
            float v1 = acc[1][r] + b1v[1];
            float v2 = acc[2][r] + b1v[2];
            float v3 = acc[3][r] + b1v[3];
            uint2v pk;
            pk[0] = pack2bf(v0, v1);
            pk[1] = pack2bf(v2, v3);
            *(uint2v*)(Q + (size_t)node * 256 + h * 128 + pp0) = pk;
        }
    }
}

// Kernel 3: out[e] = sum_pp relu(Q[r][pp] + Q[c][128+pp]) * W2p[pp] + b2  (b1 pre-folded)
// 16 lanes per edge, 4 edges per group; all 8 gathers issued before any math.
__global__ __launch_bounds__(256) void edge_kernel(
        const int* __restrict__ eli, const unsigned short* __restrict__ Q,
        const float* __restrict__ W2p, const float* __restrict__ b2,
        float* __restrict__ out, int E) {
    int g      = threadIdx.x >> 4;
    int lane16 = threadIdx.x & 15;
    int j0 = lane16 * 8;

    float2v w[4];
    #pragma unroll
    for (int k = 0; k < 4; ++k) w[k] = ((const float2v*)(W2p + j0))[k];
    float bias2 = b2[0];

    int e0 = blockIdx.x * 64 + g;

    int idx_r[4], idx_c[4];
    #pragma unroll
    for (int i = 0; i < 4; ++i) {
        int e = e0 + i * 16;
        idx_r[i] = (e < E) ? eli[e]     : 0;
        idx_c[i] = (e < E) ? eli[E + e] : 0;
    }

    uint4v u1[4], u2[4];
    #pragma unroll
    for (int i = 0; i < 4; ++i) {
        u1[i] = *(const uint4v*)(Q + (size_t)idx_r[i] * 256 + j0);
        u2[i] = *(const uint4v*)(Q + (size_t)idx_c[i] * 256 + 128 + j0);
    }

    #pragma unroll
    for (int i = 0; i < 4; ++i) {
        float2v accv = (float2v)(0.0f);
        #pragma unroll
        for (int k = 0; k < 4; ++k) {
            unsigned a1 = u1[i][k], a2 = u2[i][k];
            float2v v1, v2;
            v1[0] = __uint_as_float(a1 << 16);
            v1[1] = __uint_as_float(a1 & 0xFFFF0000u);
            v2[0] = __uint_as_float(a2 << 16);
            v2[1] = __uint_as_float(a2 & 0xFFFF0000u);
            float2v s = v1 + v2;                       // v_pk_add_f32
            s[0] = fmaxf(s[0], 0.0f);
            s[1] = fmaxf(s[1], 0.0f);
            accv[0] = fmaf(s[0], w[k][0], accv[0]);
            accv[1] = fmaf(s[1], w[k][1], accv[1]);
        }
        float acc = accv[0] + accv[1];
        acc += __shfl_xor(acc, 1);
        acc += __shfl_xor(acc, 2);
        acc += __shfl_xor(acc, 4);
        acc += __shfl_xor(acc, 8);

        int e = e0 + i * 16;
        if (lane16 == 0 && e < E) out[e] = acc + bias2;
    }
}

extern "C" void kernel_launch(void* const* d_in, const int* in_sizes, int n_in,
                              void* d_out, int out_size, void* d_ws, size_t ws_size,
                              hipStream_t stream) {
    const float* z   = (const float*)d_in[0];
    const int*   eli = (const int*)d_in[1];
    const float* W1  = (const float*)d_in[2];
    const float* b1  = (const float*)d_in[3];
    const float* W2  = (const float*)d_in[4];
    const float* b2  = (const float*)d_in[5];
    int n_nodes = in_sizes[0] / HIDDEN;       // 100000
    int E       = in_sizes[1] / 2;            // 1000000
    float* out  = (float*)d_out;

    size_t qbytes = (size_t)n_nodes * 256 * 2;
    unsigned short* Q   = (unsigned short*)d_ws;
    unsigned short* Wt  = (unsigned short*)((char*)d_ws + qbytes);
    float*          b1p = (float*)((char*)d_ws + qbytes + 256 * 128 * 2);
    float*          W2p = b1p + 128;

    prep_wt<<<128, 256, 0, stream>>>(W1, b1, W2, Wt, b1p, W2p);

    node_gemm<<<(n_nodes + 15) / 16, 256, 0, stream>>>(z, Wt, b1p, Q, n_nodes);

    edge_kernel<<<(E + 63) / 64, 256, 0, stream>>>(eli, Q, W2p, b2, out, E);
}

// Round 6
// 203.590 us; speedup vs baseline: 1.1182x; 1.1182x over previous
//
#include <hip/hip_runtime.h>
#include <hip/hip_bf16.h>
#include <stdint.h>

#define HIDDEN 128

typedef __attribute__((ext_vector_type(8))) short short8;
typedef __attribute__((ext_vector_type(4))) unsigned uint4v;
typedef __attribute__((ext_vector_type(4))) float float4v;
typedef __attribute__((ext_vector_type(2))) float float2v;
typedef __attribute__((ext_vector_type(2))) unsigned uint2v;

static __device__ __forceinline__ unsigned short f2bf(float f) {
    union { float f; unsigned u; } v; v.f = f;
    unsigned r = (v.u + 0x7FFFu + ((v.u >> 16) & 1u)) >> 16;
    return (unsigned short)r;
}

// Fast pack: round-half-up (+0x8000) then byte-perm. ±0.5 ULP like RNE.
static __device__ __forceinline__ unsigned pack2bf(float f0, float f1) {
    unsigned u0 = __float_as_uint(f0) + 0x8000u;
    unsigned u1 = __float_as_uint(f1) + 0x8000u;
    return __builtin_amdgcn_perm(u1, u0, 0x07060302u);
}

static __device__ __forceinline__ short8 pack8(float4v lo, float4v hi) {
    uint4v u;
    u[0] = pack2bf(lo[0], lo[1]);
    u[1] = pack2bf(lo[2], lo[3]);
    u[2] = pack2bf(hi[0], hi[1]);
    u[3] = pack2bf(hi[2], hi[3]);
    return *(short8*)&u;
}

// Kernel 1: build Wt (logical col-major combined weight, bf16, RNE) + permuted b1/W2.
// Combined W[k][j]: j<128 -> W1[k*128+j]; j>=128 -> W1[(128+k)*128+(j-128)]
// Wt[j*128+k] = W[k][j]. Permutation within each half: physical pp=m*8+tt <-> logical jj=tt*16+m.
__global__ void prep_wt(const float* __restrict__ W1, const float* __restrict__ b1,
                        const float* __restrict__ W2,
                        unsigned short* __restrict__ Wt,
                        float* __restrict__ b1p, float* __restrict__ W2p) {
    int idx = blockIdx.x * blockDim.x + threadIdx.x;   // 0 .. 32767
    if (idx < 256 * 128) {
        int j = idx >> 7, k = idx & 127;
        float v = (j < 128) ? W1[k * 128 + j] : W1[(128 + k) * 128 + (j - 128)];
        Wt[idx] = f2bf(v);
    }
    if (idx < 128) {
        int m = idx >> 3, tt = idx & 7;
        int jj = tt * 16 + m;
        b1p[idx] = b1[jj];
        W2p[idx] = W2[jj];
    }
}

// Kernel 2: Q[node][0:256] = z[node] @ W (+ b1 folded into first half), bf16, permuted layout.
// B-resident: wave w owns cols [w*64, w*64+64) in registers (16 short8, loaded once);
// block streams 64 nodes through 4 m-tiles. 1563 blocks = 6252 waves.
__global__ __launch_bounds__(256) void node_gemm(
        const float* __restrict__ z, const unsigned short* __restrict__ Wt,
        const float* __restrict__ b1p,
        unsigned short* __restrict__ Q, int n_nodes) {
    int lane = threadIdx.x & 63;
    int wave = threadIdx.x >> 6;
    int m = lane & 15;
    int quad = lane >> 4;
    int blockBase = blockIdx.x * 64;

    // B fragments, loaded once: cols wave*64 + t*16 + m
    short8 b[4][4];
    #pragma unroll
    for (int t = 0; t < 4; ++t) {
        const unsigned short* wp = Wt + (size_t)(wave * 64 + t * 16 + m) * HIDDEN;
        #pragma unroll
        for (int s = 0; s < 4; ++s)
            b[t][s] = *(const short8*)(wp + s * 32 + quad * 8);
    }

    int h   = wave >> 1;                      // 0: P1 half (bias folded), 1: P2 half
    int pp0 = m * 8 + (wave & 1) * 4;
    float4v b1v = (float4v)(0.0f);
    if (h == 0) b1v = *(const float4v*)(b1p + pp0);

    #pragma unroll
    for (int it = 0; it < 4; ++it) {
        int n0 = blockBase + it * 16;
        int row = n0 + m;

        short8 a[4];
        {
            bool ok = row < n_nodes;
            const float* zp = z + (size_t)row * HIDDEN + quad * 8;
            #pragma unroll
            for (int s = 0; s < 4; ++s) {
                float4v z0 = ok ? *(const float4v*)(zp + s * 32)     : (float4v)(0.0f);
                float4v z1 = ok ? *(const float4v*)(zp + s * 32 + 4) : (float4v)(0.0f);
                a[s] = pack8(z0, z1);
            }
        }

        float4v acc[4];
        #pragma unroll
        for (int t = 0; t < 4; ++t) acc[t] = (float4v)(0.0f);
        #pragma unroll
        for (int t = 0; t < 4; ++t)
            #pragma unroll
            for (int s = 0; s < 4; ++s)
                acc[t] = __builtin_amdgcn_mfma_f32_16x16x32_bf16(a[s], b[t][s], acc[t], 0, 0, 0);

        // C/D: node-row = quad*4 + r; lane's 4 col-tiles contiguous at physical pp0.
        #pragma unroll
        for (int r = 0; r < 4; ++r) {
            int node = n0 + quad * 4 + r;
            if (node < n_nodes) {
                float v0 = acc[0][r] + b1v[0];
                float v1 = acc[1][r] + b1v[1];
                float v2 = acc[2][r] + b1v[2];
                float v3 = acc[3][r] + b1v[3];
                uint2v pk;
                pk[0] = pack2bf(v0, v1);
                pk[1] = pack2bf(v2, v3);
                *(uint2v*)(Q + (size_t)node * 256 + h * 128 + pp0) = pk;
            }
        }
    }
}

// Kernel 3: out[e] = sum_pp relu(Q[r][pp] + Q[c][128+pp]) * W2p[pp] + b2  (b1 pre-folded)
// 16 lanes per edge, 8 edges per group (MLP depth 8): all 16 row-gathers issued
// before any math to maximize outstanding L2/L3 misses per wave.
__global__ __launch_bounds__(256) void edge_kernel(
        const int* __restrict__ eli, const unsigned short* __restrict__ Q,
        const float* __restrict__ W2p, const float* __restrict__ b2,
        float* __restrict__ out, int E) {
    int g      = threadIdx.x >> 4;
    int lane16 = threadIdx.x & 15;
    int j0 = lane16 * 8;

    float2v w[4];
    #pragma unroll
    for (int k = 0; k < 4; ++k) w[k] = ((const float2v*)(W2p + j0))[k];
    float bias2 = b2[0];

    int e0 = blockIdx.x * 128 + g;

    int idx_r[8], idx_c[8];
    #pragma unroll
    for (int i = 0; i < 8; ++i) {
        int e = e0 + i * 16;
        idx_r[i] = (e < E) ? eli[e]     : 0;
        idx_c[i] = (e < E) ? eli[E + e] : 0;
    }

    uint4v u1[8], u2[8];
    #pragma unroll
    for (int i = 0; i < 8; ++i) {
        u1[i] = *(const uint4v*)(Q + (size_t)idx_r[i] * 256 + j0);
        u2[i] = *(const uint4v*)(Q + (size_t)idx_c[i] * 256 + 128 + j0);
    }

    #pragma unroll
    for (int i = 0; i < 8; ++i) {
        float2v accv = (float2v)(0.0f);
        #pragma unroll
        for (int k = 0; k < 4; ++k) {
            unsigned a1 = u1[i][k], a2 = u2[i][k];
            float2v v1, v2;
            v1[0] = __uint_as_float(a1 << 16);
            v1[1] = __uint_as_float(a1 & 0xFFFF0000u);
            v2[0] = __uint_as_float(a2 << 16);
            v2[1] = __uint_as_float(a2 & 0xFFFF0000u);
            float2v s = v1 + v2;                       // v_pk_add_f32
            s[0] = fmaxf(s[0], 0.0f);
            s[1] = fmaxf(s[1], 0.0f);
            accv[0] = fmaf(s[0], w[k][0], accv[0]);
            accv[1] = fmaf(s[1], w[k][1], accv[1]);
        }
        float acc = accv[0] + accv[1];
        acc += __shfl_xor(acc, 1);
        acc += __shfl_xor(acc, 2);
        acc += __shfl_xor(acc, 4);
        acc += __shfl_xor(acc, 8);

        int e = e0 + i * 16;
        if (lane16 == 0 && e < E) out[e] = acc + bias2;
    }
}

extern "C" void kernel_launch(void* const* d_in, const int* in_sizes, int n_in,
                              void* d_out, int out_size, void* d_ws, size_t ws_size,
                              hipStream_t stream) {
    const float* z   = (const float*)d_in[0];
    const int*   eli = (const int*)d_in[1];
    const float* W1  = (const float*)d_in[2];
    const float* b1  = (const float*)d_in[3];
    const float* W2  = (const float*)d_in[4];
    const float* b2  = (const float*)d_in[5];
    int n_nodes = in_sizes[0] / HIDDEN;       // 100000
    int E       = in_sizes[1] / 2;            // 1000000
    float* out  = (float*)d_out;

    size_t qbytes = (size_t)n_nodes * 256 * 2;
    unsigned short* Q   = (unsigned short*)d_ws;
    unsigned short* Wt  = (unsigned short*)((char*)d_ws + qbytes);
    float*          b1p = (float*)((char*)d_ws + qbytes + 256 * 128 * 2);
    float*          W2p = b1p + 128;

    prep_wt<<<128, 256, 0, stream>>>(W1, b1, W2, Wt, b1p, W2p);

    node_gemm<<<(n_nodes + 63) / 64, 256, 0, stream>>>(z, Wt, b1p, Q, n_nodes);

    edge_kernel<<<(E + 127) / 128, 256, 0, stream>>>(eli, Q, W2p, b2, out, E);
}

// Round 7
// 183.852 us; speedup vs baseline: 1.2383x; 1.1074x over previous
//
#include <hip/hip_runtime.h>
#include <hip/hip_bf16.h>
#include <stdint.h>

#define HIDDEN 128
#define LDS_STRIDE 136   // shorts per col: 128 + 8 pad -> 68 words, 68%32=4 ->
                         // ds_read_b128 starts at 4*(m+q)%32: even over all banks

typedef __attribute__((ext_vector_type(8))) short short8;
typedef __attribute__((ext_vector_type(4))) unsigned uint4v;
typedef __attribute__((ext_vector_type(4))) float float4v;
typedef __attribute__((ext_vector_type(2))) float float2v;
typedef __attribute__((ext_vector_type(2))) unsigned uint2v;

static __device__ __forceinline__ unsigned short f2bf(float f) {
    union { float f; unsigned u; } v; v.f = f;
    unsigned r = (v.u + 0x7FFFu + ((v.u >> 16) & 1u)) >> 16;
    return (unsigned short)r;
}

// Fast pack: round-half-up (+0x8000) then byte-perm. ±0.5 ULP like RNE.
static __device__ __forceinline__ unsigned pack2bf(float f0, float f1) {
    unsigned u0 = __float_as_uint(f0) + 0x8000u;
    unsigned u1 = __float_as_uint(f1) + 0x8000u;
    return __builtin_amdgcn_perm(u1, u0, 0x07060302u);
}

static __device__ __forceinline__ short8 pack8(float4v lo, float4v hi) {
    uint4v u;
    u[0] = pack2bf(lo[0], lo[1]);
    u[1] = pack2bf(lo[2], lo[3]);
    u[2] = pack2bf(hi[0], hi[1]);
    u[3] = pack2bf(hi[2], hi[3]);
    return *(short8*)&u;
}

// Kernel 1: build Wt (logical col-major combined weight, bf16, RNE) + permuted b1/W2.
// Combined W[k][j]: j<128 -> W1[k*128+j]; j>=128 -> W1[(128+k)*128+(j-128)]
// Wt[j*128+k] = W[k][j]. Permutation within each half: physical pp=m*8+tt <-> logical jj=tt*16+m.
__global__ void prep_wt(const float* __restrict__ W1, const float* __restrict__ b1,
                        const float* __restrict__ W2,
                        unsigned short* __restrict__ Wt,
                        float* __restrict__ b1p, float* __restrict__ W2p) {
    int idx = blockIdx.x * blockDim.x + threadIdx.x;   // 0 .. 32767
    if (idx < 256 * 128) {
        int j = idx >> 7, k = idx & 127;
        float v = (j < 128) ? W1[k * 128 + j] : W1[(128 + k) * 128 + (j - 128)];
        Wt[idx] = f2bf(v);
    }
    if (idx < 128) {
        int m = idx >> 3, tt = idx & 7;
        int jj = tt * 16 + m;
        b1p[idx] = b1[jj];
        W2p[idx] = W2[jj];
    }
}

// Kernel 2: Q[node][0:256] = z[node] @ W (+ b1 folded into first half), bf16, permuted.
// Half-specialized blocks: block handles half h = blockIdx.x & 1; stages its 128 cols
// of Wt (32 KB -> 34.8 KB padded LDS) once; 8 waves each do a 16-node x 128-col tile
// (32 MFMAs, acc=32 VGPRs) reading B from LDS, grid-stride over tiles.
__global__ __launch_bounds__(512) void node_gemm(
        const float* __restrict__ z, const unsigned short* __restrict__ Wt,
        const float* __restrict__ b1p,
        unsigned short* __restrict__ Q, int n_nodes) {
    __shared__ unsigned short Wl[128 * LDS_STRIDE];   // 34816 B

    int tid  = threadIdx.x;
    int h    = blockIdx.x & 1;

    // Stage this half's weights: global Wt[h*16384 + chunk*8 .. +8)
    #pragma unroll
    for (int i = 0; i < 4; ++i) {
        int chunk = tid + i * 512;                 // 0..2047
        int c  = chunk >> 4;                       // local col 0..127
        int k0 = (chunk & 15) * 8;
        short8 v = *(const short8*)(Wt + h * 16384 + chunk * 8);
        *(short8*)(Wl + c * LDS_STRIDE + k0) = v;
    }
    __syncthreads();

    int lane = tid & 63;
    int wave = tid >> 6;                           // 0..7
    int m    = lane & 15;
    int quad = lane >> 4;

    float4v b1a = (float4v)(0.0f), b1b = (float4v)(0.0f);
    if (h == 0) {
        b1a = *(const float4v*)(b1p + m * 8);
        b1b = *(const float4v*)(b1p + m * 8 + 4);
    }

    int nTiles = (n_nodes + 15) >> 4;
    int tileStride = (gridDim.x >> 1) * 8;         // waves per half

    for (int tile = (blockIdx.x >> 1) * 8 + wave; tile < nTiles; tile += tileStride) {
        int nodebase = tile * 16;
        int row = nodebase + m;

        // A: lane holds A[m][k = quad*8 + j] per 32-wide k-step s
        short8 a[4];
        {
            bool ok = row < n_nodes;
            const float* zp = z + (size_t)row * HIDDEN + quad * 8;
            #pragma unroll
            for (int s = 0; s < 4; ++s) {
                float4v z0 = ok ? *(const float4v*)(zp + s * 32)     : (float4v)(0.0f);
                float4v z1 = ok ? *(const float4v*)(zp + s * 32 + 4) : (float4v)(0.0f);
                a[s] = pack8(z0, z1);
            }
        }

        float4v acc[8];
        #pragma unroll
        for (int t = 0; t < 8; ++t) acc[t] = (float4v)(0.0f);

        // B from LDS: local col c = t*16 + m, k-offset s*32 + quad*8
        #pragma unroll
        for (int t = 0; t < 8; ++t) {
            const unsigned short* wp = Wl + (t * 16 + m) * LDS_STRIDE + quad * 8;
            #pragma unroll
            for (int s = 0; s < 4; ++s) {
                short8 b = *(const short8*)(wp + s * 32);
                acc[t] = __builtin_amdgcn_mfma_f32_16x16x32_bf16(a[s], b, acc[t], 0, 0, 0);
            }
        }

        // C/D: node-row = quad*4 + r; lane's 8 col-tiles contiguous at physical m*8.
        #pragma unroll
        for (int r = 0; r < 4; ++r) {
            int node = nodebase + quad * 4 + r;
            if (node < n_nodes) {
                uint4v pk;
                pk[0] = pack2bf(acc[0][r] + b1a[0], acc[1][r] + b1a[1]);
                pk[1] = pack2bf(acc[2][r] + b1a[2], acc[3][r] + b1a[3]);
                pk[2] = pack2bf(acc[4][r] + b1b[0], acc[5][r] + b1b[1]);
                pk[3] = pack2bf(acc[6][r] + b1b[2], acc[7][r] + b1b[3]);
                *(uint4v*)(Q + (size_t)node * 256 + h * 128 + m * 8) = pk;
            }
        }
    }
}

// Kernel 3: out[e] = sum_pp relu(Q[r][pp] + Q[c][128+pp]) * W2p[pp] + b2  (b1 pre-folded)
// 16 lanes per edge, 4 edges per group (R4 config: best measured plateau).
__global__ __launch_bounds__(256) void edge_kernel(
        const int* __restrict__ eli, const unsigned short* __restrict__ Q,
        const float* __restrict__ W2p, const float* __restrict__ b2,
        float* __restrict__ out, int E) {
    int g      = threadIdx.x >> 4;
    int lane16 = threadIdx.x & 15;
    int j0 = lane16 * 8;

    float2v w[4];
    #pragma unroll
    for (int k = 0; k < 4; ++k) w[k] = ((const float2v*)(W2p + j0))[k];
    float bias2 = b2[0];

    int e0 = blockIdx.x * 64 + g;

    int idx_r[4], idx_c[4];
    #pragma unroll
    for (int i = 0; i < 4; ++i) {
        int e = e0 + i * 16;
        idx_r[i] = (e < E) ? eli[e]     : 0;
        idx_c[i] = (e < E) ? eli[E + e] : 0;
    }

    uint4v u1[4], u2[4];
    #pragma unroll
    for (int i = 0; i < 4; ++i) {
        u1[i] = *(const uint4v*)(Q + (size_t)idx_r[i] * 256 + j0);
        u2[i] = *(const uint4v*)(Q + (size_t)idx_c[i] * 256 + 128 + j0);
    }

    #pragma unroll
    for (int i = 0; i < 4; ++i) {
        float2v accv = (float2v)(0.0f);
        #pragma unroll
        for (int k = 0; k < 4; ++k) {
            unsigned a1 = u1[i][k], a2 = u2[i][k];
            float2v v1, v2;
            v1[0] = __uint_as_float(a1 << 16);
            v1[1] = __uint_as_float(a1 & 0xFFFF0000u);
            v2[0] = __uint_as_float(a2 << 16);
            v2[1] = __uint_as_float(a2 & 0xFFFF0000u);
            float2v s = v1 + v2;                       // v_pk_add_f32
            s[0] = fmaxf(s[0], 0.0f);
            s[1] = fmaxf(s[1], 0.0f);
            accv[0] = fmaf(s[0], w[k][0], accv[0]);
            accv[1] = fmaf(s[1], w[k][1], accv[1]);
        }
        float acc = accv[0] + accv[1];
        acc += __shfl_xor(acc, 1);
        acc += __shfl_xor(acc, 2);
        acc += __shfl_xor(acc, 4);
        acc += __shfl_xor(acc, 8);

        int e = e0 + i * 16;
        if (lane16 == 0 && e < E) out[e] = acc + bias2;
    }
}

extern "C" void kernel_launch(void* const* d_in, const int* in_sizes, int n_in,
                              void* d_out, int out_size, void* d_ws, size_t ws_size,
                              hipStream_t stream) {
    const float* z   = (const float*)d_in[0];
    const int*   eli = (const int*)d_in[1];
    const float* W1  = (const float*)d_in[2];
    const float* b1  = (const float*)d_in[3];
    const float* W2  = (const float*)d_in[4];
    const float* b2  = (const float*)d_in[5];
    int n_nodes = in_sizes[0] / HIDDEN;       // 100000
    int E       = in_sizes[1] / 2;            // 1000000
    float* out  = (float*)d_out;

    size_t qbytes = (size_t)n_nodes * 256 * 2;
    unsigned short* Q   = (unsigned short*)d_ws;
    unsigned short* Wt  = (unsigned short*)((char*)d_ws + qbytes);
    float*          b1p = (float*)((char*)d_ws + qbytes + 256 * 128 * 2);
    float*          W2p = b1p + 128;

    prep_wt<<<128, 256, 0, stream>>>(W1, b1, W2, Wt, b1p, W2p);

    // 1024 blocks: 512 per half, 8 waves each -> 4096 wave-tiles per half,
    // grid-stride covers 6250 tiles in 1-2 iterations.
    node_gemm<<<1024, 512, 0, stream>>>(z, Wt, b1p, Q, n_nodes);

    edge_kernel<<<(E + 63) / 64, 256, 0, stream>>>(eli, Q, W2p, b2, out, E);
}